// Round 1
// baseline (568.914 us; speedup 1.0000x reference)
//
#include <hip/hip_runtime.h>
#include <stdint.h>

#define SEQ 2048
#define NH  16
#define DK  64
#define DM  1024

typedef __bf16 bf16x8 __attribute__((ext_vector_type(8)));
typedef float  f32x4  __attribute__((ext_vector_type(4)));
typedef void __attribute__((address_space(3))) lds_void;
typedef const void __attribute__((address_space(1))) glb_void;

__device__ __forceinline__ unsigned short f2b(float f) {
  unsigned int u = __float_as_uint(f);
  u += 0x7fffu + ((u >> 16) & 1u);
  return (unsigned short)(u >> 16);
}
__device__ __forceinline__ float b2f(unsigned short h) {
  return __uint_as_float(((unsigned int)h) << 16);
}
// global->LDS direct load, 16B per lane. LDS dest = wave-uniform base + lane*16.
// as(1) cast via integer is identity for global ptrs; low 32 bits of a generic
// LDS pointer are the as(3) offset (aperture lives in the high half).
__device__ __forceinline__ void gload_lds16(const void* g, void* lds) {
  __builtin_amdgcn_global_load_lds((glb_void*)(uintptr_t)g,
                                   (lds_void*)(unsigned int)(uintptr_t)lds,
                                   16, 0, 0);
}

// ---------------- f32 -> bf16 convert, 4 elems/thread ----------------
__global__ __launch_bounds__(256) void k_cvt(const float* __restrict__ src,
                                             unsigned short* __restrict__ dst, int n4) {
  int i = blockIdx.x * 256 + threadIdx.x;
  if (i >= n4) return;
  float4 v = ((const float4*)src)[i];
  uint2 o;
  o.x = (unsigned int)f2b(v.x) | ((unsigned int)f2b(v.y) << 16);
  o.y = (unsigned int)f2b(v.z) | ((unsigned int)f2b(v.w) << 16);
  ((uint2*)dst)[i] = o;
}

// ---------------- RoPE cos/sin table: [SEQ][32] ----------------
__global__ __launch_bounds__(256) void k_tab(float2* __restrict__ tab) {
  int i = blockIdx.x * 256 + threadIdx.x;   // 0..SEQ*32-1
  int p = i >> 5, f = i & 31;
  float freq = powf(10000.0f, -(float)(2 * f) / (float)DK);
  float ang = (float)p * freq;
  tab[i] = make_float2(cosf(ang), sinf(ang));
}

// ---------------- GEMM: C = A[M][K] * B[N][K]^T (bf16 in) ----------------
// MODE 0: bf16 out, permuted to [B][NH][SEQ][DK]  (for Q/K/V)
// MODE 1: f32 out, row-major [M][N]               (final projection)
template <int MODE>
__global__ __launch_bounds__(256) void k_gemm(const unsigned short* __restrict__ A,
                                              const unsigned short* __restrict__ B,
                                              void* __restrict__ C, int M, int N, int K) {
  __shared__ __align__(16) unsigned short As[128 * 32];
  __shared__ __align__(16) unsigned short Bs[128 * 32];
  const int tid = threadIdx.x;
  const int wid = tid >> 6, lane = tid & 63;
  const int lr = lane & 15, lk = lane >> 4;
  const int wr = wid >> 1, wc = wid & 1;          // 2x2 waves, 64x64 each
  const int m0 = blockIdx.x * 128, n0 = blockIdx.y * 128;
  f32x4 acc[4][4] = {};
  for (int k0 = 0; k0 < K; k0 += 32) {
    __syncthreads();
#pragma unroll
    for (int rep = 0; rep < 2; ++rep) {
      int c = rep * 256 + tid;                    // 16B chunk id, 0..511
      int row = c >> 2, colb = (c & 3) << 3;
      gload_lds16(A + (size_t)(m0 + row) * K + k0 + colb,
                  As + (size_t)(rep * 256 + wid * 64) * 8);
      gload_lds16(B + (size_t)(n0 + row) * K + k0 + colb,
                  Bs + (size_t)(rep * 256 + wid * 64) * 8);
    }
    __syncthreads();
    bf16x8 af[4], bfv[4];
#pragma unroll
    for (int i = 0; i < 4; ++i)
      af[i] = *(const bf16x8*)&As[(wr * 64 + i * 16 + lr) * 32 + lk * 8];
#pragma unroll
    for (int j = 0; j < 4; ++j)
      bfv[j] = *(const bf16x8*)&Bs[(wc * 64 + j * 16 + lr) * 32 + lk * 8];
#pragma unroll
    for (int i = 0; i < 4; ++i)
#pragma unroll
      for (int j = 0; j < 4; ++j)
        acc[i][j] = __builtin_amdgcn_mfma_f32_16x16x32_bf16(af[i], bfv[j], acc[i][j], 0, 0, 0);
  }
  // C/D layout (m89-verified): col = lane&15, row = (lane>>4)*4 + reg
#pragma unroll
  for (int i = 0; i < 4; ++i) {
    const int rbase = m0 + wr * 64 + i * 16 + lk * 4;
#pragma unroll
    for (int j = 0; j < 4; ++j) {
      const int col = n0 + wc * 64 + j * 16 + lr;
#pragma unroll
      for (int r = 0; r < 4; ++r) {
        float v = acc[i][j][r];
        int row = rbase + r;
        if (MODE == 0) {
          int b = row >> 11, s = row & (SEQ - 1);
          int h = col >> 6, d = col & (DK - 1);
          ((unsigned short*)C)[((((size_t)b * NH + h) * SEQ) + s) * DK + d] = f2b(v);
        } else {
          ((float*)C)[(size_t)row * N + col] = v;
        }
      }
    }
  }
}

// ---------------- RoPE in place on [B][NH][SEQ][DK] bf16, 4 pairs/thread ----------------
__global__ __launch_bounds__(256) void k_rope(unsigned short* __restrict__ X,
                                              const int* __restrict__ pos,
                                              const float2* __restrict__ tab) {
  int idx = blockIdx.x * 256 + threadIdx.x;     // 0 .. B*NH*SEQ*8-1
  int i4 = idx & 7;                             // group of 4 pairs within 32
  int s = (idx >> 3) & (SEQ - 1);
  int bh = idx >> 14;                           // SEQ*8 = 2^14
  int b = bh >> 4;
  int p = pos[(b << 11) + s];
  const float2* t = tab + p * 32 + i4 * 4;
  uint4 raw = *(const uint4*)&X[(size_t)idx * 8];
  unsigned int w[4] = {raw.x, raw.y, raw.z, raw.w};
#pragma unroll
  for (int j = 0; j < 4; ++j) {
    float x1 = b2f((unsigned short)(w[j] & 0xffffu));
    float x2 = b2f((unsigned short)(w[j] >> 16));
    float2 cs = t[j];
    float o1 = x1 * cs.x - x2 * cs.y;
    float o2 = x1 * cs.y + x2 * cs.x;
    w[j] = (unsigned int)f2b(o1) | ((unsigned int)f2b(o2) << 16);
  }
  *(uint4*)&X[(size_t)idx * 8] = make_uint4(w[0], w[1], w[2], w[3]);
}

// ---------------- causal flash attention ----------------
// grid (SEQ/64, B*NH), 4 waves/block; wave w owns 16 Q rows; K-tiles of 32.
__global__ __launch_bounds__(256) void k_attn(const unsigned short* __restrict__ Q,
                                              const unsigned short* __restrict__ K,
                                              const unsigned short* __restrict__ V,
                                              unsigned short* __restrict__ O) {
  __shared__ __align__(16) unsigned short VT[64 * 32];    // V^T tile [d][k]
  __shared__ __align__(16) unsigned short Pl[4][16 * 32]; // per-wave P
  const int tid = threadIdx.x, wid = tid >> 6, lane = tid & 63;
  const int lr = lane & 15, lk = lane >> 4;
  const int q0 = blockIdx.x * 64;
  const int bh = blockIdx.y;
  const unsigned short* Qp = Q + (size_t)bh * SEQ * DK;
  const unsigned short* Kp = K + (size_t)bh * SEQ * DK;
  const unsigned short* Vp = V + (size_t)bh * SEQ * DK;
  const int qw = q0 + wid * 16;
  const bf16x8 qf0 = *(const bf16x8*)&Qp[(size_t)(qw + lr) * DK + lk * 8];
  const bf16x8 qf1 = *(const bf16x8*)&Qp[(size_t)(qw + lr) * DK + 32 + lk * 8];
  f32x4 oacc[4] = {};
  float m_[4] = {-1e30f, -1e30f, -1e30f, -1e30f};
  float l_[4] = {0.f, 0.f, 0.f, 0.f};
  const int ntiles = (q0 + 64) / 32;
  const int vr = tid >> 3, vc = (tid & 7) << 3;
  for (int kt = 0; kt < ntiles; ++kt) {
    const int kb = kt * 32;
    __syncthreads();                        // previous VT fully consumed
    { // cooperative V^T staging: 32 rows x 64 cols
      uint4 raw = *(const uint4*)&Vp[(size_t)(kb + vr) * DK + vc];
      unsigned int w[4] = {raw.x, raw.y, raw.z, raw.w};
#pragma unroll
      for (int j = 0; j < 4; ++j) {
        VT[(vc + 2 * j) * 32 + vr]     = (unsigned short)(w[j] & 0xffffu);
        VT[(vc + 2 * j + 1) * 32 + vr] = (unsigned short)(w[j] >> 16);
      }
    }
    __syncthreads();                        // VT ready
    if (kb <= qw + 15) {                    // wave-uniform causal skip
      f32x4 sa[2];
#pragma unroll
      for (int t = 0; t < 2; ++t) {
        bf16x8 kf0 = *(const bf16x8*)&Kp[(size_t)(kb + t * 16 + lr) * DK + lk * 8];
        bf16x8 kf1 = *(const bf16x8*)&Kp[(size_t)(kb + t * 16 + lr) * DK + 32 + lk * 8];
        f32x4 z = {};
        z = __builtin_amdgcn_mfma_f32_16x16x32_bf16(qf0, kf0, z, 0, 0, 0);
        z = __builtin_amdgcn_mfma_f32_16x16x32_bf16(qf1, kf1, z, 0, 0, 0);
        sa[t] = z;
      }
      // scale + causal mask (seq-index based, diagonal included)
#pragma unroll
      for (int t = 0; t < 2; ++t)
#pragma unroll
        for (int r = 0; r < 4; ++r) {
          int qrow = qw + lk * 4 + r;
          int kcol = kb + t * 16 + lr;
          float v = sa[t][r] * 0.125f;
          sa[t][r] = (kcol <= qrow) ? v : -1e30f;
        }
      float scal[4];
#pragma unroll
      for (int r = 0; r < 4; ++r) {         // row max over 32 cols (16 lanes x 2 tiles)
        float v = fmaxf(sa[0][r], sa[1][r]);
        v = fmaxf(v, __shfl_xor(v, 1));
        v = fmaxf(v, __shfl_xor(v, 2));
        v = fmaxf(v, __shfl_xor(v, 4));
        v = fmaxf(v, __shfl_xor(v, 8));
        float mn = fmaxf(m_[r], v);
        scal[r] = __expf(m_[r] - mn);
        m_[r] = mn;
      }
#pragma unroll
      for (int r = 0; r < 4; ++r) {
        float p0 = __expf(sa[0][r] - m_[r]);
        float p1 = __expf(sa[1][r] - m_[r]);
        sa[0][r] = p0; sa[1][r] = p1;
        float v = p0 + p1;
        v += __shfl_xor(v, 1);
        v += __shfl_xor(v, 2);
        v += __shfl_xor(v, 4);
        v += __shfl_xor(v, 8);
        l_[r] = l_[r] * scal[r] + v;
      }
#pragma unroll
      for (int dt = 0; dt < 4; ++dt)
#pragma unroll
        for (int r = 0; r < 4; ++r) oacc[dt][r] *= scal[r];
      // P -> LDS (C-layout) -> back as A-fragment
#pragma unroll
      for (int t = 0; t < 2; ++t)
#pragma unroll
        for (int r = 0; r < 4; ++r)
          Pl[wid][(lk * 4 + r) * 32 + t * 16 + lr] = f2b(sa[t][r]);
      asm volatile("s_waitcnt lgkmcnt(0)" ::: "memory");
      const bf16x8 pa = *(const bf16x8*)&Pl[wid][lr * 32 + lk * 8];
#pragma unroll
      for (int dt = 0; dt < 4; ++dt) {
        bf16x8 vf = *(const bf16x8*)&VT[(dt * 16 + lr) * 32 + lk * 8];
        oacc[dt] = __builtin_amdgcn_mfma_f32_16x16x32_bf16(pa, vf, oacc[dt], 0, 0, 0);
      }
    }
  }
  const int b = bh >> 4, h = bh & (NH - 1);
  float inv[4];
#pragma unroll
  for (int r = 0; r < 4; ++r) inv[r] = 1.0f / l_[r];
#pragma unroll
  for (int dt = 0; dt < 4; ++dt)
#pragma unroll
    for (int r = 0; r < 4; ++r) {
      int q = qw + lk * 4 + r;
      O[((size_t)(b * SEQ + q)) * DM + h * DK + dt * 16 + lr] = f2b(oacc[dt][r] * inv[r]);
    }
}

extern "C" void kernel_launch(void* const* d_in, const int* in_sizes, int n_in,
                              void* d_out, int out_size, void* d_ws, size_t ws_size,
                              hipStream_t stream) {
  const float* x = (const float*)d_in[0];
  const int* tp = (const int*)d_in[1];
  const float* W[4] = {(const float*)d_in[2], (const float*)d_in[3],
                       (const float*)d_in[4], (const float*)d_in[5]};
  // workspace layout (bf16 buffers as ushort), ~88.5 MB total
  unsigned short* xb = (unsigned short*)d_ws;              // [8192][1024]
  unsigned short* wb0 = xb + (size_t)8192 * 1024;          // Wq [1024][1024]
  unsigned short* wb1 = wb0 + (size_t)1024 * 1024;
  unsigned short* wb2 = wb1 + (size_t)1024 * 1024;
  unsigned short* wb3 = wb2 + (size_t)1024 * 1024;
  float2* tab = (float2*)(wb3 + (size_t)1024 * 1024);      // [2048][32]
  unsigned short* Qb = (unsigned short*)(tab + SEQ * 32);  // [B][H][S][64]
  unsigned short* Kb = Qb + (size_t)8192 * 1024;
  unsigned short* Vb = Kb + (size_t)8192 * 1024;
  unsigned short* Ob = Vb + (size_t)8192 * 1024;           // [B][S][D]

  k_cvt<<<8192, 256, 0, stream>>>(x, xb, 2097152);
  k_cvt<<<1024, 256, 0, stream>>>(W[0], wb0, 262144);
  k_cvt<<<1024, 256, 0, stream>>>(W[1], wb1, 262144);
  k_cvt<<<1024, 256, 0, stream>>>(W[2], wb2, 262144);
  k_cvt<<<1024, 256, 0, stream>>>(W[3], wb3, 262144);
  k_tab<<<SEQ * 32 / 256, 256, 0, stream>>>(tab);
  k_gemm<0><<<dim3(64, 8), 256, 0, stream>>>(xb, wb0, Qb, 8192, 1024, 1024);
  k_gemm<0><<<dim3(64, 8), 256, 0, stream>>>(xb, wb1, Kb, 8192, 1024, 1024);
  k_gemm<0><<<dim3(64, 8), 256, 0, stream>>>(xb, wb2, Vb, 8192, 1024, 1024);
  k_rope<<<4096, 256, 0, stream>>>(Qb, tp, tab);
  k_rope<<<4096, 256, 0, stream>>>(Kb, tp, tab);
  k_attn<<<dim3(SEQ / 64, 4 * NH), 256, 0, stream>>>(Qb, Kb, Vb, Ob);
  k_gemm<1><<<dim3(64, 8), 256, 0, stream>>>(Ob, wb3, d_out, 8192, 1024, 1024);
}

// Round 2
// 343.995 us; speedup vs baseline: 1.6538x; 1.6538x over previous
//
#include <hip/hip_runtime.h>
#include <stdint.h>

#define SEQ 2048
#define NH  16
#define DK  64
#define DM  1024
#define QBLK 128
#define C2SM 0.18033688011112042f   // 0.125 * log2(e): folds 1/sqrt(64) into exp2

typedef __bf16 bf16x8 __attribute__((ext_vector_type(8)));
typedef float  f32x4  __attribute__((ext_vector_type(4)));
typedef void __attribute__((address_space(3))) lds_void;
typedef const void __attribute__((address_space(1))) glb_void;

__device__ __forceinline__ unsigned short f2b(float f) {
  unsigned int u = __float_as_uint(f);
  u += 0x7fffu + ((u >> 16) & 1u);
  return (unsigned short)(u >> 16);
}
__device__ __forceinline__ float b2f(unsigned short h) {
  return __uint_as_float(((unsigned int)h) << 16);
}
__device__ __forceinline__ void gload_lds16(const void* g, void* lds) {
  __builtin_amdgcn_global_load_lds((glb_void*)(uintptr_t)g,
                                   (lds_void*)(unsigned int)(uintptr_t)lds,
                                   16, 0, 0);
}
// 16-lane row reductions on the VALU pipe (DPP row_ror), not LDS (ds_swizzle).
template <int CTRL>
__device__ __forceinline__ float dpp_ror(float x) {
  int i = __float_as_int(x);
  return __int_as_float(__builtin_amdgcn_update_dpp(i, i, CTRL, 0xf, 0xf, false));
}
__device__ __forceinline__ float redmax16(float v) {
  v = fmaxf(v, dpp_ror<0x121>(v));
  v = fmaxf(v, dpp_ror<0x122>(v));
  v = fmaxf(v, dpp_ror<0x124>(v));
  v = fmaxf(v, dpp_ror<0x128>(v));
  return v;
}
__device__ __forceinline__ float redsum16(float v) {
  v += dpp_ror<0x121>(v);
  v += dpp_ror<0x122>(v);
  v += dpp_ror<0x124>(v);
  v += dpp_ror<0x128>(v);
  return v;
}

// ---------------- f32 -> bf16 convert ----------------
__global__ __launch_bounds__(256) void k_cvt(const float* __restrict__ src,
                                             unsigned short* __restrict__ dst, int n4) {
  int i = blockIdx.x * 256 + threadIdx.x;
  if (i >= n4) return;
  float4 v = ((const float4*)src)[i];
  uint2 o;
  o.x = (unsigned int)f2b(v.x) | ((unsigned int)f2b(v.y) << 16);
  o.y = (unsigned int)f2b(v.z) | ((unsigned int)f2b(v.w) << 16);
  ((uint2*)dst)[i] = o;
}

// ---------------- RoPE cos/sin table: [SEQ][32] ----------------
__global__ __launch_bounds__(256) void k_tab(float2* __restrict__ tab) {
  int i = blockIdx.x * 256 + threadIdx.x;
  int p = i >> 5, f = i & 31;
  float freq = powf(10000.0f, -(float)(2 * f) / (float)DK);
  float ang = (float)p * freq;
  tab[i] = make_float2(cosf(ang), sinf(ang));
}

// ---------------- GEMM: C = A[M][K] * B[N][K]^T (bf16 in) ----------------
// MODE 0: bf16 out, permuted to [B][NH][SEQ][DK]     (Q/K)
// MODE 1: f32 out, row-major [M][N]                  (final projection)
// MODE 2: bf16 out, rows are neurons -> [B][NH][DK][SEQ]  (V^T directly)
template <int MODE>
__global__ __launch_bounds__(256) void k_gemm(const unsigned short* __restrict__ A,
                                              const unsigned short* __restrict__ B,
                                              void* __restrict__ C, int M, int N, int K) {
  __shared__ __align__(16) unsigned short As[128 * 32];
  __shared__ __align__(16) unsigned short Bs[128 * 32];
  const int tid = threadIdx.x;
  const int wid = tid >> 6, lane = tid & 63;
  const int lr = lane & 15, lk = lane >> 4;
  const int wr = wid >> 1, wc = wid & 1;
  const int m0 = blockIdx.x * 128, n0 = blockIdx.y * 128;
  f32x4 acc[4][4] = {};
  for (int k0 = 0; k0 < K; k0 += 32) {
    __syncthreads();
#pragma unroll
    for (int rep = 0; rep < 2; ++rep) {
      int c = rep * 256 + tid;
      int row = c >> 2, colb = (c & 3) << 3;
      gload_lds16(A + (size_t)(m0 + row) * K + k0 + colb,
                  As + (size_t)(rep * 256 + wid * 64) * 8);
      gload_lds16(B + (size_t)(n0 + row) * K + k0 + colb,
                  Bs + (size_t)(rep * 256 + wid * 64) * 8);
    }
    __syncthreads();
    bf16x8 af[4], bfv[4];
#pragma unroll
    for (int i = 0; i < 4; ++i)
      af[i] = *(const bf16x8*)&As[(wr * 64 + i * 16 + lr) * 32 + lk * 8];
#pragma unroll
    for (int j = 0; j < 4; ++j)
      bfv[j] = *(const bf16x8*)&Bs[(wc * 64 + j * 16 + lr) * 32 + lk * 8];
#pragma unroll
    for (int i = 0; i < 4; ++i)
#pragma unroll
      for (int j = 0; j < 4; ++j)
        acc[i][j] = __builtin_amdgcn_mfma_f32_16x16x32_bf16(af[i], bfv[j], acc[i][j], 0, 0, 0);
  }
#pragma unroll
  for (int i = 0; i < 4; ++i) {
    const int rbase = m0 + wr * 64 + i * 16 + lk * 4;
#pragma unroll
    for (int j = 0; j < 4; ++j) {
      const int col = n0 + wc * 64 + j * 16 + lr;
#pragma unroll
      for (int r = 0; r < 4; ++r) {
        float v = acc[i][j][r];
        int row = rbase + r;
        if (MODE == 0) {
          int b = row >> 11, s = row & (SEQ - 1);
          int h = col >> 6, d = col & (DK - 1);
          ((unsigned short*)C)[((((size_t)b * NH + h) * SEQ) + s) * DK + d] = f2b(v);
        } else if (MODE == 1) {
          ((float*)C)[(size_t)row * N + col] = v;
        } else {
          int h = row >> 6, d = row & (DK - 1);
          int b = col >> 11, s = col & (SEQ - 1);
          ((unsigned short*)C)[(((size_t)b * NH + h) * DK + d) * SEQ + s] = f2b(v);
        }
      }
    }
  }
}

// ---------------- RoPE in place on [B][NH][SEQ][DK] bf16 ----------------
__global__ __launch_bounds__(256) void k_rope(unsigned short* __restrict__ X,
                                              const int* __restrict__ pos,
                                              const float2* __restrict__ tab) {
  int idx = blockIdx.x * 256 + threadIdx.x;
  int i4 = idx & 7;
  int s = (idx >> 3) & (SEQ - 1);
  int bh = idx >> 14;
  int b = bh >> 4;
  int p = pos[(b << 11) + s];
  const float2* t = tab + p * 32 + i4 * 4;
  uint4 raw = *(const uint4*)&X[(size_t)idx * 8];
  unsigned int w[4] = {raw.x, raw.y, raw.z, raw.w};
#pragma unroll
  for (int j = 0; j < 4; ++j) {
    float x1 = b2f((unsigned short)(w[j] & 0xffffu));
    float x2 = b2f((unsigned short)(w[j] >> 16));
    float2 cs = t[j];
    float o1 = x1 * cs.x - x2 * cs.y;
    float o2 = x1 * cs.y + x2 * cs.x;
    w[j] = (unsigned int)f2b(o1) | ((unsigned int)f2b(o2) << 16);
  }
  *(uint4*)&X[(size_t)idx * 8] = make_uint4(w[0], w[1], w[2], w[3]);
}

// ---------------- causal flash attention ----------------
// grid (SEQ/128, B*NH), 4 waves; wave owns 32 q rows; KV tiles of 64.
// K tile [64 k][64 d] and VT tile [64 d][64 k] staged via global_load_lds with
// XOR-swizzled 16B slots (slot ^= row&7); source pre-swizzled, reads swizzled.
__global__ __launch_bounds__(256) void k_attn(const unsigned short* __restrict__ Q,
                                              const unsigned short* __restrict__ K,
                                              const unsigned short* __restrict__ VT,
                                              unsigned short* __restrict__ O) {
  __shared__ __align__(16) unsigned short Ks[64 * 64];
  __shared__ __align__(16) unsigned short Vs[64 * 64];
  __shared__ __align__(16) unsigned short Ps[4][32 * 64];
  const int tid = threadIdx.x, wid = tid >> 6, lane = tid & 63;
  const int lr = lane & 15, lk = lane >> 4;
  const int q0 = blockIdx.x * QBLK;
  const int bh = blockIdx.y;
  const unsigned short* Qp = Q + (size_t)bh * SEQ * DK;
  const unsigned short* Kp = K + (size_t)bh * SEQ * DK;
  const unsigned short* Vp = VT + (size_t)bh * DK * SEQ;   // [64][SEQ]
  const int qw = q0 + wid * 32;
  bf16x8 qf[2][2];
#pragma unroll
  for (int f = 0; f < 2; ++f)
#pragma unroll
    for (int c = 0; c < 2; ++c)
      qf[f][c] = *(const bf16x8*)&Qp[(size_t)(qw + f * 16 + lr) * DK + c * 32 + lk * 8];
  f32x4 oacc[2][4] = {};
  float m_[2][4], l_[2][4];
#pragma unroll
  for (int f = 0; f < 2; ++f)
#pragma unroll
    for (int r = 0; r < 4; ++r) { m_[f][r] = -1e30f; l_[f][r] = 0.f; }
  const int ntiles = q0 / 64 + 2;
  unsigned short* Pw = &Ps[wid][0];
  for (int kt = 0; kt < ntiles; ++kt) {
    const int kb = kt * 64;
    __syncthreads();                       // prev tile fully consumed
#pragma unroll
    for (int rep = 0; rep < 2; ++rep) {    // stage K + VT, swizzled source
      const int c = rep * 256 + tid;
      const int row = c >> 3;
      const int slot = (c & 7) ^ (row & 7);
      gload_lds16(Kp + (size_t)(kb + row) * DK + slot * 8,
                  Ks + (size_t)(rep * 256 + wid * 64) * 8);
      gload_lds16(Vp + (size_t)row * SEQ + kb + slot * 8,
                  Vs + (size_t)(rep * 256 + wid * 64) * 8);
    }
    __syncthreads();                       // staged (vmcnt drained by barrier)
    if (kb > qw + 31) continue;            // wave-uniform causal skip
    // ---- QK^T ----
    f32x4 sa[2][4];
#pragma unroll
    for (int t = 0; t < 4; ++t) {
      const int krow = t * 16 + lr;
      bf16x8 kf0 = *(const bf16x8*)((const char*)Ks + krow * 128 + (((0 + lk) ^ (krow & 7)) << 4));
      bf16x8 kf1 = *(const bf16x8*)((const char*)Ks + krow * 128 + (((4 + lk) ^ (krow & 7)) << 4));
#pragma unroll
      for (int f = 0; f < 2; ++f) {
        f32x4 z = {};
        z = __builtin_amdgcn_mfma_f32_16x16x32_bf16(qf[f][0], kf0, z, 0, 0, 0);
        z = __builtin_amdgcn_mfma_f32_16x16x32_bf16(qf[f][1], kf1, z, 0, 0, 0);
        sa[f][t] = z;
      }
    }
    if (kb + 64 > qw) {                    // only the diagonal tile masks
#pragma unroll
      for (int f = 0; f < 2; ++f) {
        const int qrow = qw + f * 16 + lk * 4;
#pragma unroll
        for (int t = 0; t < 4; ++t) {
          const int kcol = kb + t * 16 + lr;
#pragma unroll
          for (int r = 0; r < 4; ++r)
            if (kcol > qrow + r) sa[f][t][r] = -1e30f;
        }
      }
    }
    // ---- online softmax (raw scores; 1/8 scale folded into exp2 constant) ----
#pragma unroll
    for (int f = 0; f < 2; ++f) {
#pragma unroll
      for (int r = 0; r < 4; ++r) {
        float mx = fmaxf(fmaxf(sa[f][0][r], sa[f][1][r]), fmaxf(sa[f][2][r], sa[f][3][r]));
        mx = redmax16(mx);
        const float mn = fmaxf(m_[f][r], mx);
        const float sc = __builtin_amdgcn_exp2f((m_[f][r] - mn) * C2SM);
        m_[f][r] = mn;
        float sum = 0.f;
#pragma unroll
        for (int t = 0; t < 4; ++t) {
          const float p = __builtin_amdgcn_exp2f((sa[f][t][r] - mn) * C2SM);
          sa[f][t][r] = p;
          sum += p;
        }
        sum = redsum16(sum);
        l_[f][r] = l_[f][r] * sc + sum;
#pragma unroll
        for (int d = 0; d < 4; ++d) oacc[f][d][r] *= sc;
      }
    }
    // ---- P -> LDS (swizzled 128B rows), per-wave buffer ----
#pragma unroll
    for (int f = 0; f < 2; ++f)
#pragma unroll
      for (int r = 0; r < 4; ++r) {
        const int qr = f * 16 + lk * 4 + r;
#pragma unroll
        for (int t = 0; t < 4; ++t) {
          const int kc = t * 16 + lr;
          *(unsigned short*)((char*)Pw + qr * 128 + ((((kc >> 3) ^ (qr & 7))) << 4) +
                             ((kc & 7) << 1)) = f2b(sa[f][t][r]);
        }
      }
    asm volatile("s_waitcnt lgkmcnt(0)" ::: "memory");
    // ---- PV ----
    bf16x8 vf[4][2];
#pragma unroll
    for (int d = 0; d < 4; ++d) {
      const int vrow = d * 16 + lr;
      vf[d][0] = *(const bf16x8*)((const char*)Vs + vrow * 128 + (((0 + lk) ^ (vrow & 7)) << 4));
      vf[d][1] = *(const bf16x8*)((const char*)Vs + vrow * 128 + (((4 + lk) ^ (vrow & 7)) << 4));
    }
#pragma unroll
    for (int f = 0; f < 2; ++f) {
      const int prow = f * 16 + lr;
      bf16x8 pa0 = *(const bf16x8*)((const char*)Pw + prow * 128 + (((0 + lk) ^ (prow & 7)) << 4));
      bf16x8 pa1 = *(const bf16x8*)((const char*)Pw + prow * 128 + (((4 + lk) ^ (prow & 7)) << 4));
#pragma unroll
      for (int d = 0; d < 4; ++d) {
        oacc[f][d] = __builtin_amdgcn_mfma_f32_16x16x32_bf16(pa0, vf[d][0], oacc[f][d], 0, 0, 0);
        oacc[f][d] = __builtin_amdgcn_mfma_f32_16x16x32_bf16(pa1, vf[d][1], oacc[f][d], 0, 0, 0);
      }
    }
  }
  // ---- epilogue ----
  const int b = bh >> 4, h = bh & (NH - 1);
#pragma unroll
  for (int f = 0; f < 2; ++f)
#pragma unroll
    for (int r = 0; r < 4; ++r) {
      const float inv = 1.0f / l_[f][r];
      const int q = qw + f * 16 + lk * 4 + r;
#pragma unroll
      for (int d = 0; d < 4; ++d)
        O[((size_t)(b * SEQ + q)) * DM + h * DK + d * 16 + lr] = f2b(oacc[f][d][r] * inv);
    }
}

extern "C" void kernel_launch(void* const* d_in, const int* in_sizes, int n_in,
                              void* d_out, int out_size, void* d_ws, size_t ws_size,
                              hipStream_t stream) {
  const float* x = (const float*)d_in[0];
  const int* tp = (const int*)d_in[1];
  const float* W[4] = {(const float*)d_in[2], (const float*)d_in[3],
                       (const float*)d_in[4], (const float*)d_in[5]};
  unsigned short* xb = (unsigned short*)d_ws;              // [8192][1024]
  unsigned short* wb0 = xb + (size_t)8192 * 1024;
  unsigned short* wb1 = wb0 + (size_t)1024 * 1024;
  unsigned short* wb2 = wb1 + (size_t)1024 * 1024;
  unsigned short* wb3 = wb2 + (size_t)1024 * 1024;
  float2* tab = (float2*)(wb3 + (size_t)1024 * 1024);      // [2048][32]
  unsigned short* Qb = (unsigned short*)(tab + SEQ * 32);  // [B][H][S][64]
  unsigned short* Kb = Qb + (size_t)8192 * 1024;           // [B][H][S][64]
  unsigned short* VTb = Kb + (size_t)8192 * 1024;          // [B][H][64][S]
  unsigned short* Ob = VTb + (size_t)8192 * 1024;          // [B][S][D]

  k_cvt<<<8192, 256, 0, stream>>>(x, xb, 2097152);
  k_cvt<<<1024, 256, 0, stream>>>(W[0], wb0, 262144);
  k_cvt<<<1024, 256, 0, stream>>>(W[1], wb1, 262144);
  k_cvt<<<1024, 256, 0, stream>>>(W[2], wb2, 262144);
  k_cvt<<<1024, 256, 0, stream>>>(W[3], wb3, 262144);
  k_tab<<<SEQ * 32 / 256, 256, 0, stream>>>(tab);
  k_gemm<0><<<dim3(64, 8), 256, 0, stream>>>(xb, wb0, Qb, 8192, 1024, 1024);
  k_gemm<0><<<dim3(64, 8), 256, 0, stream>>>(xb, wb1, Kb, 8192, 1024, 1024);
  k_gemm<2><<<dim3(8, 64), 256, 0, stream>>>(wb2, xb, VTb, 1024, 8192, 1024);
  k_rope<<<4096, 256, 0, stream>>>(Qb, tp, tab);
  k_rope<<<4096, 256, 0, stream>>>(Kb, tp, tab);
  k_attn<<<dim3(SEQ / QBLK, 4 * NH), 256, 0, stream>>>(Qb, Kb, VTb, Ob);
  k_gemm<1><<<dim3(64, 8), 256, 0, stream>>>(Ob, wb3, d_out, 8192, 1024, 1024);
}

// Round 3
// 268.187 us; speedup vs baseline: 2.1213x; 1.2827x over previous
//
#include <hip/hip_runtime.h>
#include <stdint.h>

#define SEQ 2048
#define NH  16
#define DK  64
#define DM  1024
#define C2SM 0.18033688011112042f   // 0.125 * log2(e): folds 1/sqrt(64) into exp2

typedef __bf16 bf16x8 __attribute__((ext_vector_type(8)));
typedef float  f32x4  __attribute__((ext_vector_type(4)));
typedef void __attribute__((address_space(3))) lds_void;
typedef const void __attribute__((address_space(1))) glb_void;

__device__ __forceinline__ unsigned short f2b(float f) {
  unsigned int u = __float_as_uint(f);
  u += 0x7fffu + ((u >> 16) & 1u);
  return (unsigned short)(u >> 16);
}
__device__ __forceinline__ float b2f(unsigned short h) {
  return __uint_as_float(((unsigned int)h) << 16);
}
__device__ __forceinline__ void gload_lds16(const void* g, void* lds) {
  __builtin_amdgcn_global_load_lds((glb_void*)(uintptr_t)g,
                                   (lds_void*)(unsigned int)(uintptr_t)lds,
                                   16, 0, 0);
}
// 16-lane row reductions on the VALU pipe (DPP row_ror), not LDS (ds_swizzle).
template <int CTRL>
__device__ __forceinline__ float dpp_ror(float x) {
  int i = __float_as_int(x);
  return __int_as_float(__builtin_amdgcn_update_dpp(i, i, CTRL, 0xf, 0xf, false));
}
__device__ __forceinline__ float redmax16(float v) {
  v = fmaxf(v, dpp_ror<0x121>(v));
  v = fmaxf(v, dpp_ror<0x122>(v));
  v = fmaxf(v, dpp_ror<0x124>(v));
  v = fmaxf(v, dpp_ror<0x128>(v));
  return v;
}
__device__ __forceinline__ float redsum16(float v) {
  v += dpp_ror<0x121>(v);
  v += dpp_ror<0x122>(v);
  v += dpp_ror<0x124>(v);
  v += dpp_ror<0x128>(v);
  return v;
}

// ---------------- f32 -> bf16 convert ----------------
__global__ __launch_bounds__(256) void k_cvt(const float* __restrict__ src,
                                             unsigned short* __restrict__ dst, int n4) {
  int i = blockIdx.x * 256 + threadIdx.x;
  if (i >= n4) return;
  float4 v = ((const float4*)src)[i];
  uint2 o;
  o.x = (unsigned int)f2b(v.x) | ((unsigned int)f2b(v.y) << 16);
  o.y = (unsigned int)f2b(v.z) | ((unsigned int)f2b(v.w) << 16);
  ((uint2*)dst)[i] = o;
}

// ---------------- RoPE cos/sin table: [SEQ][32] ----------------
__global__ __launch_bounds__(256) void k_tab(float2* __restrict__ tab) {
  int i = blockIdx.x * 256 + threadIdx.x;
  int p = i >> 5, f = i & 31;
  float freq = powf(10000.0f, -(float)(2 * f) / (float)DK);
  float ang = (float)p * freq;
  tab[i] = make_float2(cosf(ang), sinf(ang));
}

// ---------------- GEMM: C = A[M][K] * B[N][K]^T (bf16 in) ----------------
// MODE 0: bf16 out, permuted to [B][NH][SEQ][DK]     (Q/K)
// MODE 1: f32 out, row-major [M][N]                  (final projection)
// MODE 2: bf16 out, rows are neurons -> [B][NH][DK][SEQ]  (V^T directly)
template <int MODE>
__global__ __launch_bounds__(256) void k_gemm(const unsigned short* __restrict__ A,
                                              const unsigned short* __restrict__ B,
                                              void* __restrict__ C, int M, int N, int K) {
  __shared__ __align__(16) unsigned short As[128 * 32];
  __shared__ __align__(16) unsigned short Bs[128 * 32];
  const int tid = threadIdx.x;
  const int wid = tid >> 6, lane = tid & 63;
  const int lr = lane & 15, lk = lane >> 4;
  const int wr = wid >> 1, wc = wid & 1;
  const int m0 = blockIdx.x * 128, n0 = blockIdx.y * 128;
  f32x4 acc[4][4] = {};
  for (int k0 = 0; k0 < K; k0 += 32) {
    __syncthreads();
#pragma unroll
    for (int rep = 0; rep < 2; ++rep) {
      int c = rep * 256 + tid;
      int row = c >> 2, colb = (c & 3) << 3;
      gload_lds16(A + (size_t)(m0 + row) * K + k0 + colb,
                  As + (size_t)(rep * 256 + wid * 64) * 8);
      gload_lds16(B + (size_t)(n0 + row) * K + k0 + colb,
                  Bs + (size_t)(rep * 256 + wid * 64) * 8);
    }
    __syncthreads();
    bf16x8 af[4], bfv[4];
#pragma unroll
    for (int i = 0; i < 4; ++i)
      af[i] = *(const bf16x8*)&As[(wr * 64 + i * 16 + lr) * 32 + lk * 8];
#pragma unroll
    for (int j = 0; j < 4; ++j)
      bfv[j] = *(const bf16x8*)&Bs[(wc * 64 + j * 16 + lr) * 32 + lk * 8];
#pragma unroll
    for (int i = 0; i < 4; ++i)
#pragma unroll
      for (int j = 0; j < 4; ++j)
        acc[i][j] = __builtin_amdgcn_mfma_f32_16x16x32_bf16(af[i], bfv[j], acc[i][j], 0, 0, 0);
  }
#pragma unroll
  for (int i = 0; i < 4; ++i) {
    const int rbase = m0 + wr * 64 + i * 16 + lk * 4;
#pragma unroll
    for (int j = 0; j < 4; ++j) {
      const int col = n0 + wc * 64 + j * 16 + lr;
#pragma unroll
      for (int r = 0; r < 4; ++r) {
        float v = acc[i][j][r];
        int row = rbase + r;
        if (MODE == 0) {
          int b = row >> 11, s = row & (SEQ - 1);
          int h = col >> 6, d = col & (DK - 1);
          ((unsigned short*)C)[((((size_t)b * NH + h) * SEQ) + s) * DK + d] = f2b(v);
        } else if (MODE == 1) {
          ((float*)C)[(size_t)row * N + col] = v;
        } else {
          int h = row >> 6, d = row & (DK - 1);
          int b = col >> 11, s = col & (SEQ - 1);
          ((unsigned short*)C)[(((size_t)b * NH + h) * DK + d) * SEQ + s] = f2b(v);
        }
      }
    }
  }
}

// ---------------- RoPE in place on [B][NH][SEQ][DK] bf16 ----------------
__global__ __launch_bounds__(256) void k_rope(unsigned short* __restrict__ X,
                                              const int* __restrict__ pos,
                                              const float2* __restrict__ tab) {
  int idx = blockIdx.x * 256 + threadIdx.x;
  int i4 = idx & 7;
  int s = (idx >> 3) & (SEQ - 1);
  int bh = idx >> 14;
  int b = bh >> 4;
  int p = pos[(b << 11) + s];
  const float2* t = tab + p * 32 + i4 * 4;
  uint4 raw = *(const uint4*)&X[(size_t)idx * 8];
  unsigned int w[4] = {raw.x, raw.y, raw.z, raw.w};
#pragma unroll
  for (int j = 0; j < 4; ++j) {
    float x1 = b2f((unsigned short)(w[j] & 0xffffu));
    float x2 = b2f((unsigned short)(w[j] >> 16));
    float2 cs = t[j];
    float o1 = x1 * cs.x - x2 * cs.y;
    float o2 = x1 * cs.y + x2 * cs.x;
    w[j] = (unsigned int)f2b(o1) | ((unsigned int)f2b(o2) << 16);
  }
  *(uint4*)&X[(size_t)idx * 8] = make_uint4(w[0], w[1], w[2], w[3]);
}

// ---------------- causal flash attention, fold-balanced ----------------
// grid (16, B*NH), 4 waves. Each block runs two q-tiles of 64 rows:
// qt = ix (light) then qt = 31-ix (heavy): (ix+1) + (32-ix) = 33 K-tiles/block,
// exactly equal work across the whole grid. Wave owns 16 q-rows.
__global__ __launch_bounds__(256) void k_attn(const unsigned short* __restrict__ Q,
                                              const unsigned short* __restrict__ K,
                                              const unsigned short* __restrict__ VT,
                                              unsigned short* __restrict__ O) {
  __shared__ __align__(16) unsigned short Ks[64 * 64];
  __shared__ __align__(16) unsigned short Vs[64 * 64];
  __shared__ __align__(16) unsigned short Ps[4][16 * 64];
  const int tid = threadIdx.x, wid = tid >> 6, lane = tid & 63;
  const int lr = lane & 15, lk = lane >> 4;
  const int bh = blockIdx.y;
  const unsigned short* Qp = Q + (size_t)bh * SEQ * DK;
  const unsigned short* Kp = K + (size_t)bh * SEQ * DK;
  const unsigned short* Vp = VT + (size_t)bh * DK * SEQ;   // [64][SEQ]
  const int b = bh >> 4, h = bh & (NH - 1);
  unsigned short* Pw = &Ps[wid][0];
  // staging coords (per thread, per rep): 512 chunks of 16B per 8KB tile
  const int srow0 = tid >> 3, srow1 = (256 + tid) >> 3;
  const int sslot0 = (tid & 7) ^ (srow0 & 7), sslot1 = (tid & 7) ^ (srow1 & 7);

#pragma unroll
  for (int pass = 0; pass < 2; ++pass) {
    const int qt = pass == 0 ? (int)blockIdx.x : 31 - (int)blockIdx.x;
    const int q0 = qt * 64;
    const int qw = q0 + wid * 16;
    bf16x8 qf0 = *(const bf16x8*)&Qp[(size_t)(qw + lr) * DK + lk * 8];
    bf16x8 qf1 = *(const bf16x8*)&Qp[(size_t)(qw + lr) * DK + 32 + lk * 8];
    f32x4 oacc[4] = {};
    float m_[4] = {-1e30f, -1e30f, -1e30f, -1e30f};
    float l_[4] = {0.f, 0.f, 0.f, 0.f};
    const int ntiles = qt + 1;
    for (int kt = 0; kt < ntiles; ++kt) {
      const int kb = kt * 64;
      __syncthreads();                       // prev tile fully consumed
      gload_lds16(Kp + (size_t)(kb + srow0) * DK + sslot0 * 8, Ks + (size_t)(wid * 64) * 8);
      gload_lds16(Kp + (size_t)(kb + srow1) * DK + sslot1 * 8, Ks + (size_t)(256 + wid * 64) * 8);
      gload_lds16(Vp + (size_t)srow0 * SEQ + kb + sslot0 * 8, Vs + (size_t)(wid * 64) * 8);
      gload_lds16(Vp + (size_t)srow1 * SEQ + kb + sslot1 * 8, Vs + (size_t)(256 + wid * 64) * 8);
      __syncthreads();                       // staged (vmcnt drained by barrier)
      // ---- QK^T ----
      f32x4 sa[4];
      __builtin_amdgcn_s_setprio(1);
#pragma unroll
      for (int t = 0; t < 4; ++t) {
        const int krow = t * 16 + lr;
        bf16x8 kf0 = *(const bf16x8*)((const char*)Ks + krow * 128 + (((0 + lk) ^ (krow & 7)) << 4));
        bf16x8 kf1 = *(const bf16x8*)((const char*)Ks + krow * 128 + (((4 + lk) ^ (krow & 7)) << 4));
        f32x4 z = {};
        z = __builtin_amdgcn_mfma_f32_16x16x32_bf16(qf0, kf0, z, 0, 0, 0);
        z = __builtin_amdgcn_mfma_f32_16x16x32_bf16(qf1, kf1, z, 0, 0, 0);
        sa[t] = z;
      }
      __builtin_amdgcn_s_setprio(0);
      if (kt == ntiles - 1) {                // only the diagonal tile masks
        const int qrow = qw + lk * 4;
#pragma unroll
        for (int t = 0; t < 4; ++t) {
          const int kcol = kb + t * 16 + lr;
#pragma unroll
          for (int r = 0; r < 4; ++r)
            if (kcol > qrow + r) sa[t][r] = -1e30f;
        }
      }
      // ---- online softmax with defer-max (skip rescale when max stable) ----
      float mx[4];
#pragma unroll
      for (int r = 0; r < 4; ++r) {
        float v = fmaxf(fmaxf(sa[0][r], sa[1][r]), fmaxf(sa[2][r], sa[3][r]));
        mx[r] = redmax16(v);
      }
      bool ok = (mx[0] <= m_[0] + 16.f) && (mx[1] <= m_[1] + 16.f) &&
                (mx[2] <= m_[2] + 16.f) && (mx[3] <= m_[3] + 16.f);
      if (!__all(ok)) {
#pragma unroll
        for (int r = 0; r < 4; ++r) {
          const float mn = fmaxf(m_[r], mx[r]);
          const float sc = __builtin_amdgcn_exp2f((m_[r] - mn) * C2SM);
          m_[r] = mn;
          l_[r] *= sc;
#pragma unroll
          for (int d = 0; d < 4; ++d) oacc[d][r] *= sc;
        }
      }
#pragma unroll
      for (int r = 0; r < 4; ++r) {
        const float mc = m_[r] * C2SM;
        float s0 = __builtin_amdgcn_exp2f(__builtin_fmaf(sa[0][r], C2SM, -mc));
        float s1 = __builtin_amdgcn_exp2f(__builtin_fmaf(sa[1][r], C2SM, -mc));
        float s2 = __builtin_amdgcn_exp2f(__builtin_fmaf(sa[2][r], C2SM, -mc));
        float s3 = __builtin_amdgcn_exp2f(__builtin_fmaf(sa[3][r], C2SM, -mc));
        sa[0][r] = s0; sa[1][r] = s1; sa[2][r] = s2; sa[3][r] = s3;
        l_[r] += redsum16((s0 + s1) + (s2 + s3));
      }
      // ---- P -> LDS (swizzled 128B rows), per-wave buffer ----
#pragma unroll
      for (int r = 0; r < 4; ++r) {
        const int qr = lk * 4 + r;
#pragma unroll
        for (int t = 0; t < 4; ++t) {
          const int kc = t * 16 + lr;
          *(unsigned short*)((char*)Pw + qr * 128 + ((((kc >> 3) ^ (qr & 7))) << 4) +
                             ((kc & 7) << 1)) = f2b(sa[t][r]);
        }
      }
      asm volatile("s_waitcnt lgkmcnt(0)" ::: "memory");
      // ---- PV ----
      const int prow = lr;
      bf16x8 pa0 = *(const bf16x8*)((const char*)Pw + prow * 128 + (((0 + lk) ^ (prow & 7)) << 4));
      bf16x8 pa1 = *(const bf16x8*)((const char*)Pw + prow * 128 + (((4 + lk) ^ (prow & 7)) << 4));
      __builtin_amdgcn_s_setprio(1);
#pragma unroll
      for (int d = 0; d < 4; ++d) {
        const int vrow = d * 16 + lr;
        bf16x8 vf0 = *(const bf16x8*)((const char*)Vs + vrow * 128 + (((0 + lk) ^ (vrow & 7)) << 4));
        bf16x8 vf1 = *(const bf16x8*)((const char*)Vs + vrow * 128 + (((4 + lk) ^ (vrow & 7)) << 4));
        oacc[d] = __builtin_amdgcn_mfma_f32_16x16x32_bf16(pa0, vf0, oacc[d], 0, 0, 0);
        oacc[d] = __builtin_amdgcn_mfma_f32_16x16x32_bf16(pa1, vf1, oacc[d], 0, 0, 0);
      }
      __builtin_amdgcn_s_setprio(0);
    }
    // ---- epilogue for this pass ----
#pragma unroll
    for (int r = 0; r < 4; ++r) {
      const float inv = 1.0f / l_[r];
      const int q = qw + lk * 4 + r;
#pragma unroll
      for (int d = 0; d < 4; ++d)
        O[((size_t)(b * SEQ + q)) * DM + h * DK + d * 16 + lr] = f2b(oacc[d][r] * inv);
    }
    __syncthreads();                         // Ks/Vs reused by next pass
  }
}

extern "C" void kernel_launch(void* const* d_in, const int* in_sizes, int n_in,
                              void* d_out, int out_size, void* d_ws, size_t ws_size,
                              hipStream_t stream) {
  const float* x = (const float*)d_in[0];
  const int* tp = (const int*)d_in[1];
  const float* W[4] = {(const float*)d_in[2], (const float*)d_in[3],
                       (const float*)d_in[4], (const float*)d_in[5]};
  unsigned short* xb = (unsigned short*)d_ws;              // [8192][1024]
  unsigned short* wb0 = xb + (size_t)8192 * 1024;
  unsigned short* wb1 = wb0 + (size_t)1024 * 1024;
  unsigned short* wb2 = wb1 + (size_t)1024 * 1024;
  unsigned short* wb3 = wb2 + (size_t)1024 * 1024;
  float2* tab = (float2*)(wb3 + (size_t)1024 * 1024);      // [2048][32]
  unsigned short* Qb = (unsigned short*)(tab + SEQ * 32);  // [B][H][S][64]
  unsigned short* Kb = Qb + (size_t)8192 * 1024;           // [B][H][S][64]
  unsigned short* VTb = Kb + (size_t)8192 * 1024;          // [B][H][64][S]
  unsigned short* Ob = VTb + (size_t)8192 * 1024;          // [B][S][D]

  k_cvt<<<8192, 256, 0, stream>>>(x, xb, 2097152);
  k_cvt<<<1024, 256, 0, stream>>>(W[0], wb0, 262144);
  k_cvt<<<1024, 256, 0, stream>>>(W[1], wb1, 262144);
  k_cvt<<<1024, 256, 0, stream>>>(W[2], wb2, 262144);
  k_cvt<<<1024, 256, 0, stream>>>(W[3], wb3, 262144);
  k_tab<<<SEQ * 32 / 256, 256, 0, stream>>>(tab);
  k_gemm<0><<<dim3(64, 8), 256, 0, stream>>>(xb, wb0, Qb, 8192, 1024, 1024);
  k_gemm<0><<<dim3(64, 8), 256, 0, stream>>>(xb, wb1, Kb, 8192, 1024, 1024);
  k_gemm<2><<<dim3(8, 64), 256, 0, stream>>>(wb2, xb, VTb, 1024, 8192, 1024);
  k_rope<<<4096, 256, 0, stream>>>(Qb, tp, tab);
  k_rope<<<4096, 256, 0, stream>>>(Kb, tp, tab);
  k_attn<<<dim3(16, 4 * NH), 256, 0, stream>>>(Qb, Kb, VTb, Ob);
  k_gemm<1><<<dim3(64, 8), 256, 0, stream>>>(Ob, wb3, d_out, 8192, 1024, 1024);
}

// Round 4
// 210.462 us; speedup vs baseline: 2.7032x; 1.2743x over previous
//
#include <hip/hip_runtime.h>
#include <stdint.h>

#define SEQ 2048
#define NH  16
#define DK  64
#define DM  1024
#define C2SM 0.18033688011112042f   // 0.125 * log2(e): folds 1/sqrt(64) into exp2

typedef __bf16 bf16x8 __attribute__((ext_vector_type(8)));
typedef float  f32x4  __attribute__((ext_vector_type(4)));
typedef float  f32x16 __attribute__((ext_vector_type(16)));
typedef int    iv2    __attribute__((ext_vector_type(2)));
typedef void __attribute__((address_space(3))) lds_void;
typedef const void __attribute__((address_space(1))) glb_void;

__device__ __forceinline__ unsigned short f2b(float f) {
  unsigned int u = __float_as_uint(f);
  u += 0x7fffu + ((u >> 16) & 1u);
  return (unsigned short)(u >> 16);
}
__device__ __forceinline__ float b2f(unsigned short h) {
  return __uint_as_float(((unsigned int)h) << 16);
}
__device__ __forceinline__ void gload_lds16(const void* g, void* lds) {
  __builtin_amdgcn_global_load_lds((glb_void*)(uintptr_t)g,
                                   (lds_void*)(unsigned int)(uintptr_t)lds,
                                   16, 0, 0);
}
// pack two f32 -> one u32 of two bf16 (RNE), single VALU op (no builtin, m240)
__device__ __forceinline__ unsigned int cvtpk(float lo, float hi) {
  unsigned int r;
  asm("v_cvt_pk_bf16_f32 %0, %1, %2" : "=v"(r) : "v"(lo), "v"(hi));
  return r;
}
__device__ __forceinline__ iv2 pl32swap(int a, int b) {
  return __builtin_amdgcn_permlane32_swap(a, b, false, false);
}

// ---------------- f32 -> bf16 convert (x) ----------------
__global__ __launch_bounds__(256) void k_cvt(const float* __restrict__ src,
                                             unsigned short* __restrict__ dst, int n4) {
  int i = blockIdx.x * 256 + threadIdx.x;
  if (i >= n4) return;
  float4 v = ((const float4*)src)[i];
  uint2 o;
  o.x = (unsigned int)f2b(v.x) | ((unsigned int)f2b(v.y) << 16);
  o.y = (unsigned int)f2b(v.z) | ((unsigned int)f2b(v.w) << 16);
  ((uint2*)dst)[i] = o;
}

// ---------------- all 4 weights -> contiguous bf16 ----------------
__global__ __launch_bounds__(256) void k_cvtw(const float* __restrict__ w0,
                                              const float* __restrict__ w1,
                                              const float* __restrict__ w2,
                                              const float* __restrict__ w3,
                                              unsigned short* __restrict__ dst) {
  int i = blockIdx.x * 256 + threadIdx.x;   // 0..2^20-1 (float4 units)
  const float* s = (i < 524288) ? ((i < 262144) ? w0 : w1)
                                : ((i < 786432) ? w2 : w3);
  float4 v = ((const float4*)s)[i & 262143];
  uint2 o;
  o.x = (unsigned int)f2b(v.x) | ((unsigned int)f2b(v.y) << 16);
  o.y = (unsigned int)f2b(v.z) | ((unsigned int)f2b(v.w) << 16);
  ((uint2*)dst)[i] = o;
}

// ---------------- RoPE cos/sin table: [SEQ][32] ----------------
__global__ __launch_bounds__(256) void k_tab(float2* __restrict__ tab) {
  int i = blockIdx.x * 256 + threadIdx.x;
  int p = i >> 5, f = i & 31;
  float freq = powf(10000.0f, -(float)(2 * f) / (float)DK);
  float ang = (float)p * freq;
  tab[i] = make_float2(cosf(ang), sinf(ang));
}

// ---------------- GEMM: C = A[M][K] * B[N][K]^T (bf16 in) ----------------
// MODE 0: bf16 out; N=2048 (Wq;Wk fused), col>>10 picks Q/K buffer, permuted
//         to [B][NH][SEQ][DK]
// MODE 1: f32 out, row-major [M][N]                  (final projection)
// MODE 2: bf16 out, rows are neurons -> [B][NH][DK][SEQ]  (V^T directly)
template <int MODE>
__global__ __launch_bounds__(256) void k_gemm(const unsigned short* __restrict__ A,
                                              const unsigned short* __restrict__ B,
                                              void* __restrict__ C, int M, int N, int K) {
  __shared__ __align__(16) unsigned short As[128 * 32];
  __shared__ __align__(16) unsigned short Bs[128 * 32];
  const int tid = threadIdx.x;
  const int wid = tid >> 6, lane = tid & 63;
  const int lr = lane & 15, lk = lane >> 4;
  const int wr = wid >> 1, wc = wid & 1;
  const int m0 = blockIdx.x * 128, n0 = blockIdx.y * 128;
  f32x4 acc[4][4] = {};
  for (int k0 = 0; k0 < K; k0 += 32) {
    __syncthreads();
#pragma unroll
    for (int rep = 0; rep < 2; ++rep) {
      int c = rep * 256 + tid;
      int row = c >> 2, colb = (c & 3) << 3;
      gload_lds16(A + (size_t)(m0 + row) * K + k0 + colb,
                  As + (size_t)(rep * 256 + wid * 64) * 8);
      gload_lds16(B + (size_t)(n0 + row) * K + k0 + colb,
                  Bs + (size_t)(rep * 256 + wid * 64) * 8);
    }
    __syncthreads();
    bf16x8 af[4], bfv[4];
#pragma unroll
    for (int i = 0; i < 4; ++i)
      af[i] = *(const bf16x8*)&As[(wr * 64 + i * 16 + lr) * 32 + lk * 8];
#pragma unroll
    for (int j = 0; j < 4; ++j)
      bfv[j] = *(const bf16x8*)&Bs[(wc * 64 + j * 16 + lr) * 32 + lk * 8];
#pragma unroll
    for (int i = 0; i < 4; ++i)
#pragma unroll
      for (int j = 0; j < 4; ++j)
        acc[i][j] = __builtin_amdgcn_mfma_f32_16x16x32_bf16(af[i], bfv[j], acc[i][j], 0, 0, 0);
  }
#pragma unroll
  for (int i = 0; i < 4; ++i) {
    const int rbase = m0 + wr * 64 + i * 16 + lk * 4;
#pragma unroll
    for (int j = 0; j < 4; ++j) {
      const int col = n0 + wc * 64 + j * 16 + lr;
#pragma unroll
      for (int r = 0; r < 4; ++r) {
        float v = acc[i][j][r];
        int row = rbase + r;
        if (MODE == 0) {
          int b = row >> 11, s = row & (SEQ - 1);
          int t = col >> 10;                 // 0 = Q, 1 = K
          int h = (col >> 6) & 15, d = col & 63;
          ((unsigned short*)C)[(size_t)t * 8388608 +
                               ((((size_t)b * NH + h) * SEQ) + s) * DK + d] = f2b(v);
        } else if (MODE == 1) {
          ((float*)C)[(size_t)row * N + col] = v;
        } else {
          int h = row >> 6, d = row & (DK - 1);
          int b = col >> 11, s = col & (SEQ - 1);
          ((unsigned short*)C)[(((size_t)b * NH + h) * DK + d) * SEQ + s] = f2b(v);
        }
      }
    }
  }
}

// ---------------- RoPE in place on Q and K ([B][NH][SEQ][DK] bf16, contiguous) ----------------
__global__ __launch_bounds__(256) void k_rope(unsigned short* __restrict__ QK,
                                              const int* __restrict__ pos,
                                              const float2* __restrict__ tab) {
  int g = blockIdx.x * 256 + threadIdx.x;       // 0..2^21-1
  unsigned short* X = QK + (size_t)(g >> 20) * 8388608;
  int idx = g & 0xFFFFF;
  int i4 = idx & 7;
  int s = (idx >> 3) & (SEQ - 1);
  int b = (idx >> 14) >> 4;
  int p = pos[(b << 11) + s];
  const float2* t = tab + p * 32 + i4 * 4;
  uint4 raw = *(const uint4*)&X[(size_t)idx * 8];
  unsigned int w[4] = {raw.x, raw.y, raw.z, raw.w};
#pragma unroll
  for (int j = 0; j < 4; ++j) {
    float x1 = b2f((unsigned short)(w[j] & 0xffffu));
    float x2 = b2f((unsigned short)(w[j] >> 16));
    float2 cs = t[j];
    float o1 = x1 * cs.x - x2 * cs.y;
    float o2 = x1 * cs.y + x2 * cs.x;
    w[j] = (unsigned int)f2b(o1) | ((unsigned int)f2b(o2) << 16);
  }
  *(uint4*)&X[(size_t)idx * 8] = make_uint4(w[0], w[1], w[2], w[3]);
}

// ---------------- causal flash attention: swapped 32x32, in-register softmax ----------------
// grid (8, B*NH), 4 waves x 32 q-rows (QBLK=128). Fold-paired q-tiles:
// qt = ix then 15-ix -> (2qt+2)+(2(15-qt)+2) = 34 K-tiles per block, uniform.
// Swapped QK^T: sa = mfma(K,Q) -> lane&31 = q-row, regs = kcols. Softmax fully
// in-register (lane pair l/l+32 holds a q-row); P->A-frag via cvt_pk +
// permlane32_swap (T12); PV = mfma(V^T, P) keeps q = lane&31.
__global__ __launch_bounds__(256) void k_attn(const unsigned short* __restrict__ Q,
                                              const unsigned short* __restrict__ K,
                                              const unsigned short* __restrict__ VT,
                                              unsigned short* __restrict__ O) {
  __shared__ __align__(16) unsigned short Ks[64 * 64];
  __shared__ __align__(16) unsigned short Vs[64 * 64];
  const int tid = threadIdx.x, wid = tid >> 6, lane = tid & 63;
  const int l31 = lane & 31, hi = lane >> 5;
  const int bh = blockIdx.y;
  const unsigned short* Qp = Q + (size_t)bh * SEQ * DK;
  const unsigned short* Kp = K + (size_t)bh * SEQ * DK;
  const unsigned short* Vp = VT + (size_t)bh * DK * SEQ;   // [64 d][SEQ]
  const int b = bh >> 4, h = bh & (NH - 1);
  const int srow0 = tid >> 3, srow1 = (256 + tid) >> 3;
  const int sslot0 = (tid & 7) ^ (srow0 & 7), sslot1 = (tid & 7) ^ (srow1 & 7);

#pragma unroll
  for (int pass = 0; pass < 2; ++pass) {
    const int qt = pass ? 15 - (int)blockIdx.x : (int)blockIdx.x;
    const int q0 = qt * 128;
    const int qw = q0 + wid * 32;
    const int qrow = qw + l31;
    bf16x8 qf[4];
#pragma unroll
    for (int ks = 0; ks < 4; ++ks)
      qf[ks] = *(const bf16x8*)&Qp[(size_t)qrow * DK + ks * 16 + hi * 8];
    f32x16 oacc[2] = {};
    float m_ = -1e30f, l_ = 0.f;
    const int ntiles = 2 * qt + 2;
    for (int kt = 0; kt < ntiles; ++kt) {
      const int kb = kt * 64;
      __syncthreads();                       // prev tile fully consumed
      gload_lds16(Kp + (size_t)(kb + srow0) * DK + sslot0 * 8, Ks + (size_t)(wid * 64) * 8);
      gload_lds16(Kp + (size_t)(kb + srow1) * DK + sslot1 * 8, Ks + (size_t)(256 + wid * 64) * 8);
      gload_lds16(Vp + (size_t)srow0 * SEQ + kb + sslot0 * 8, Vs + (size_t)(wid * 64) * 8);
      gload_lds16(Vp + (size_t)srow1 * SEQ + kb + sslot1 * 8, Vs + (size_t)(256 + wid * 64) * 8);
      __syncthreads();                       // staged
      if (kb > qw + 31) continue;            // wave-uniform causal skip
      // ---- QK^T (swapped): sa[kg] regs = kcols kg*32 + (r&3)+8(r>>2)+4hi ----
      f32x16 sa[2];
      __builtin_amdgcn_s_setprio(1);
#pragma unroll
      for (int kg = 0; kg < 2; ++kg) {
        const int krow = kg * 32 + l31;
        f32x16 z = {};
#pragma unroll
        for (int ks = 0; ks < 4; ++ks) {
          bf16x8 kf = *(const bf16x8*)((const char*)Ks + krow * 128 +
                                       (((2 * ks + hi) ^ (krow & 7)) << 4));
          z = __builtin_amdgcn_mfma_f32_32x32x16_bf16(kf, qf[ks], z, 0, 0, 0);
        }
        sa[kg] = z;
      }
      __builtin_amdgcn_s_setprio(0);
      // ---- causal mask (diagonal-crossing tiles only) ----
      if (kb + 64 > qw) {
        const int th0 = qrow - kb - 4 * hi;
#pragma unroll
        for (int kg = 0; kg < 2; ++kg) {
          const int th = th0 - kg * 32;
#pragma unroll
          for (int r = 0; r < 16; ++r) {
            const int cst = (r & 3) + 8 * (r >> 2);
            if (cst > th) sa[kg][r] = -1e30f;
          }
        }
      }
      // ---- row max: in-register tree + lane-pair swap ----
      float mx;
      {
        float a0 = fmaxf(fmaxf(sa[0][0], sa[0][1]), fmaxf(sa[0][2], sa[0][3]));
        float a1 = fmaxf(fmaxf(sa[0][4], sa[0][5]), fmaxf(sa[0][6], sa[0][7]));
        float a2 = fmaxf(fmaxf(sa[0][8], sa[0][9]), fmaxf(sa[0][10], sa[0][11]));
        float a3 = fmaxf(fmaxf(sa[0][12], sa[0][13]), fmaxf(sa[0][14], sa[0][15]));
        float a4 = fmaxf(fmaxf(sa[1][0], sa[1][1]), fmaxf(sa[1][2], sa[1][3]));
        float a5 = fmaxf(fmaxf(sa[1][4], sa[1][5]), fmaxf(sa[1][6], sa[1][7]));
        float a6 = fmaxf(fmaxf(sa[1][8], sa[1][9]), fmaxf(sa[1][10], sa[1][11]));
        float a7 = fmaxf(fmaxf(sa[1][12], sa[1][13]), fmaxf(sa[1][14], sa[1][15]));
        mx = fmaxf(fmaxf(fmaxf(a0, a1), fmaxf(a2, a3)),
                   fmaxf(fmaxf(a4, a5), fmaxf(a6, a7)));
        iv2 t = pl32swap(__float_as_int(mx), __float_as_int(mx));
        mx = fmaxf(__int_as_float(t.x), __int_as_float(t.y));
      }
      // ---- defer-max: rescale only when running max moved by > 16 (raw) ----
      if (!__all(mx <= m_ + 16.f)) {
        const float mn = fmaxf(m_, mx);
        const float sc = __builtin_amdgcn_exp2f((m_ - mn) * C2SM);
        m_ = mn;
        l_ *= sc;
#pragma unroll
        for (int vg = 0; vg < 2; ++vg)
#pragma unroll
          for (int r = 0; r < 16; ++r) oacc[vg][r] *= sc;
      }
      // ---- exp + row sum ----
      const float mc = m_ * C2SM;
      float sum = 0.f;
#pragma unroll
      for (int kg = 0; kg < 2; ++kg)
#pragma unroll
        for (int r = 0; r < 16; ++r) {
          const float p = __builtin_amdgcn_exp2f(__builtin_fmaf(sa[kg][r], C2SM, -mc));
          sa[kg][r] = p;
          sum += p;
        }
      {
        iv2 t = pl32swap(__float_as_int(sum), __float_as_int(sum));
        l_ += __int_as_float(t.x) + __int_as_float(t.y);
      }
      // ---- PV: P->bf16 A-frag via cvt_pk + permlane32_swap, mfma(V^T, P) ----
      __builtin_amdgcn_s_setprio(1);
#pragma unroll
      for (int kg = 0; kg < 2; ++kg)
#pragma unroll
        for (int ks2 = 0; ks2 < 2; ++ks2) {
          const int rb = ks2 * 8;
          unsigned wA = cvtpk(sa[kg][rb + 0], sa[kg][rb + 1]);
          unsigned wB = cvtpk(sa[kg][rb + 4], sa[kg][rb + 5]);
          unsigned wC = cvtpk(sa[kg][rb + 2], sa[kg][rb + 3]);
          unsigned wD = cvtpk(sa[kg][rb + 6], sa[kg][rb + 7]);
          iv2 r0 = pl32swap((int)wA, (int)wB);
          iv2 r1 = pl32swap((int)wC, (int)wD);
          union { uint4 u; bf16x8 v; } pu;
          pu.u = make_uint4((unsigned)r0.x, (unsigned)r1.x, (unsigned)r0.y, (unsigned)r1.y);
          const int ks = kg * 2 + ks2;
#pragma unroll
          for (int vg = 0; vg < 2; ++vg) {
            const int vrow = vg * 32 + l31;
            bf16x8 vf = *(const bf16x8*)((const char*)Vs + vrow * 128 +
                                         (((2 * ks + hi) ^ (vrow & 7)) << 4));
            oacc[vg] = __builtin_amdgcn_mfma_f32_32x32x16_bf16(vf, pu.v, oacc[vg], 0, 0, 0);
          }
        }
      __builtin_amdgcn_s_setprio(0);
    }
    // ---- epilogue: d = vg*32 + 8j + 4hi + 0..3, packed dwordx2 stores ----
    const float inv = 1.0f / l_;
    unsigned short* Orow = O + ((size_t)(b * SEQ + qrow)) * DM + h * DK;
#pragma unroll
    for (int vg = 0; vg < 2; ++vg)
#pragma unroll
      for (int j = 0; j < 4; ++j) {
        unsigned lo = cvtpk(oacc[vg][4 * j + 0] * inv, oacc[vg][4 * j + 1] * inv);
        unsigned hh = cvtpk(oacc[vg][4 * j + 2] * inv, oacc[vg][4 * j + 3] * inv);
        *(uint2*)&Orow[vg * 32 + 8 * j + 4 * hi] = make_uint2(lo, hh);
      }
    __syncthreads();                          // Ks/Vs reused by next pass
  }
}

extern "C" void kernel_launch(void* const* d_in, const int* in_sizes, int n_in,
                              void* d_out, int out_size, void* d_ws, size_t ws_size,
                              hipStream_t stream) {
  const float* x = (const float*)d_in[0];
  const int* tp = (const int*)d_in[1];
  const float* W[4] = {(const float*)d_in[2], (const float*)d_in[3],
                       (const float*)d_in[4], (const float*)d_in[5]};
  unsigned short* xb = (unsigned short*)d_ws;              // [8192][1024]
  unsigned short* wb0 = xb + (size_t)8192 * 1024;          // Wq;Wk;Wv;Wo contiguous
  unsigned short* wb2 = wb0 + (size_t)2 * 1024 * 1024;
  unsigned short* wb3 = wb2 + (size_t)1024 * 1024;
  float2* tab = (float2*)(wb3 + (size_t)1024 * 1024);      // [2048][32]
  unsigned short* Qb = (unsigned short*)(tab + SEQ * 32);  // [B][H][S][64]
  unsigned short* Kb = Qb + (size_t)8192 * 1024;           // [B][H][S][64]
  unsigned short* VTb = Kb + (size_t)8192 * 1024;          // [B][H][64][S]
  unsigned short* Ob = VTb + (size_t)8192 * 1024;          // [B][S][D]

  k_cvt<<<8192, 256, 0, stream>>>(x, xb, 2097152);
  k_cvtw<<<4096, 256, 0, stream>>>(W[0], W[1], W[2], W[3], wb0);
  k_tab<<<256, 256, 0, stream>>>(tab);
  k_gemm<0><<<dim3(64, 16), 256, 0, stream>>>(xb, wb0, Qb, 8192, 2048, 1024);
  k_gemm<2><<<dim3(8, 64), 256, 0, stream>>>(wb2, xb, VTb, 1024, 8192, 1024);
  k_rope<<<8192, 256, 0, stream>>>(Qb, tp, tab);
  k_attn<<<dim3(8, 4 * NH), 256, 0, stream>>>(Qb, Kb, VTb, Ob);
  k_gemm<1><<<dim3(64, 8), 256, 0, stream>>>(Ob, wb3, d_out, 8192, 1024, 1024);
}